// Round 9
// baseline (130.674 us; speedup 1.0000x reference)
//
#include <hip/hip_runtime.h>
#include <hip/hip_bf16.h>

// MoE fused block, MI355X gfx950.
// Shapes: B=2, C=256, T*H*W=16384, E=4, K=2. All inputs fp32, output fp32.
//
// R13 -> R14: dense-GEMM1. Key identity: scattering H with the gate weight
// for ALL 64 positions (wg=0 for non-selected) writes exactly the zeros the
// zero-fill produced -> the sparse machinery is redundant. Deleted: ballot
// phase (+1 barrier), plist/zlist/WgtG/mcnt, zero-fill, mt dispatch, gathered
// aoff. GEMM1 = fixed 4-tile loop: uniform 8-MFMA/kc regions (no more thin
// 2*mt regions with poor load-latency cover), regular conflict-free Xs reads,
// uniform work across WGs. Cost: +23% MFMA work -- free at 21% MfmaUtil.
// GEMM2 back to ring-2 (R13's ring-4 was -6%). Wgt stored e-major [4][64]
// for vector reads in scatter + epilogue. Output bit-identical to R12.
// Operating point unchanged: MT=64, 512x512, 2 WGs/CU, 64+64 regs.

#define C_DIM 256
#define S_DIM 16384          // T*H*W
#define E_DIM 4
#define MT 64                // positions per workgroup
#define XST 264              // Xs/Hs row stride in shorts (16B-aligned rows)
#define WFRAG_ELEMS 262144   // elements per prepacked weight tensor (4*16*8*64*8)

typedef __attribute__((ext_vector_type(8))) short bf16x8;
typedef __attribute__((ext_vector_type(4))) float f32x4;

__device__ __forceinline__ short bfq(float f) {
  __hip_bfloat16 h = __float2bfloat16(f);
  return *(short*)&h;
}

// Prepack: dst[(half,e,nt,kc,lane,j)] = src[(e*256 + nt*16 + (lane&15))*256
//                                           + kc*32 + (lane>>4)*8 + j]
// B-operand fragment layout for mfma_f32_16x16x32_bf16: n=lane&15, k=(lane>>4)*8+j.
// 32 consecutive threads read one contiguous 1KB source row (fully coalesced);
// the 16B fragment stores scatter (fire-and-forget).
__global__ __launch_bounds__(256) void prepack_kernel(
    const float* __restrict__ w1, const float* __restrict__ w2,
    __hip_bfloat16* __restrict__ dst)
{
  int o8   = blockIdx.x * 256 + threadIdx.x;  // 0 .. 65535 (8-elem chunks)
  int half = o8 >> 15;                        // 0: w1, 1: w2
  int idx  = o8 & 32767;
  int j    = idx & 31;                        // 8-float chunk within source row
  int rowid= idx >> 5;                        // e*256 + nt*16 + row, 0..1023
  int e    = rowid >> 8;
  int nt   = (rowid >> 4) & 15;
  int row  = rowid & 15;
  int kc   = j >> 2;
  int col8 = j & 3;
  int lane = (col8 << 4) | row;
  const float* src = half ? w2 : w1;
  const float* s = src + rowid * 256 + j * 8;
  const float4 v0 = *(const float4*)s;
  const float4 v1 = *(const float4*)(s + 4);
  bf16x8 outv = {bfq(v0.x), bfq(v0.y), bfq(v0.z), bfq(v0.w),
                 bfq(v1.x), bfq(v1.y), bfq(v1.z), bfq(v1.w)};
  int chunk = ((e*16 + nt)*8 + kc)*64 + lane;
  *(bf16x8*)((short*)dst + half*WFRAG_ELEMS + chunk*8) = outv;
}

// Dense GEMM1 over all 4 M-tiles; barrier (protecting Hs readers of the
// previous expert's GEMM2) sits BETWEEN the MFMA loop and the H-scatter.
// Ring-2 weight prefetch; setprio(1) across the MFMA cluster (T5).
// Scatter applies the gate weight for ALL positions: wg=0 rows write exact
// zeros, replacing the old zero-fill + sparse gather machinery.
__device__ __forceinline__ void gemm1_dense(
    const short* XsS, short* HsS, const short* w1e, const float* b1e,
    const float* WgtE, int wv, int r, int q, bool dosync)
{
  f32x4 hacc[4][2];
#pragma unroll
  for (int i = 0; i < 4; ++i)
#pragma unroll
    for (int j = 0; j < 2; ++j) hacc[i][j] = (f32x4){0.f, 0.f, 0.f, 0.f};

  bf16x8 bw[2][2];
#pragma unroll
  for (int t = 0; t < 2; ++t) bw[0][t] = *(const bf16x8*)(w1e + (t*8 + 0)*512);
  __builtin_amdgcn_s_setprio(1);
#pragma unroll
  for (int kc = 0; kc < 8; ++kc) {
    if (kc < 7) {
#pragma unroll
      for (int t = 0; t < 2; ++t)
        bw[(kc+1)&1][t] = *(const bf16x8*)(w1e + (t*8 + kc + 1)*512);
    }
    bf16x8 a[4];
#pragma unroll
    for (int Mt = 0; Mt < 4; ++Mt)
      a[Mt] = *(const bf16x8*)(XsS + (Mt*16 + r)*XST + kc*32 + q*8);
#pragma unroll
    for (int Mt = 0; Mt < 4; ++Mt)
#pragma unroll
      for (int t = 0; t < 2; ++t)
        hacc[Mt][t] = __builtin_amdgcn_mfma_f32_16x16x32_bf16(a[Mt], bw[kc&1][t], hacc[Mt][t], 0, 0, 0);
  }
  __builtin_amdgcn_s_setprio(0);

  if (dosync) __syncthreads();   // prev expert's GEMM2 done reading Hs

  // epilogue: +b1, fast SiLU, scale by gate weight (0 for non-selected
  // positions -> writes exact zeros), scatter to Hs. p = Mt*16+q*4+reg.
#pragma unroll
  for (int Mt = 0; Mt < 4; ++Mt) {
    const f32x4 wg = *(const f32x4*)(WgtE + Mt*16 + q*4);
#pragma unroll
    for (int t = 0; t < 2; ++t) {
      const int n = wv*32 + t*16 + r;
      const float bias = b1e[n];
#pragma unroll
      for (int reg = 0; reg < 4; ++reg) {
        const int p = Mt*16 + q*4 + reg;
        const float z = hacc[Mt][t][reg] + bias;
        const float s = __builtin_amdgcn_rcpf(1.0f + __expf(-z));
        HsS[p*XST + n] = bfq(z * s * wg[reg]);
      }
    }
  }
}

__global__ __launch_bounds__(512, 4) void moe_fused_kernel(
    const float* __restrict__ x,
    const float* __restrict__ gate_w,
    const float* __restrict__ gate_b,
    const float* __restrict__ b1,
    const float* __restrict__ b2,
    const __hip_bfloat16* __restrict__ wp,   // [W1P | W2P] prepacked bf16
    float* __restrict__ out)
{
  // pool (67584 B): Xs (33792) + Hs (33792).
  // Gate fp64 partials (16KB) alias the Hs region before its first use.
  __shared__ __align__(16) char pool[2 * MT * XST * 2];
  __shared__ __align__(16) float Wgt[4][MT];   // gate weights, e-major

  short* XsS = (short*)pool;
  short* HsS = (short*)(pool + MT * XST * 2);

  const int tid  = threadIdx.x;
  const int lane = tid & 63;
  const int wv   = tid >> 6;     // wave 0..7: owns n-slice [wv*32, wv*32+32)
  const int r    = lane & 15;
  const int q    = lane >> 4;

  const int g  = blockIdx.x;
  const int b  = g >> 8;                 // 256 workgroups per batch
  const int s0 = (g & 255) * MT;
  const float* xb = x + (size_t)b * C_DIM * S_DIM + s0;

  const short* W1P = (const short*)wp;
  const short* W2P = (const short*)wp + WFRAG_ELEMS;

  // ---- FUSED stage X + gate partials: wave wv owns channels [wv*32, wv*32+32),
  //      lane = position. 32 coalesced scalar loads; fp64 gate dot from regs. ----
  {
    const int p  = lane;
    const int c0 = wv * 32;
    float xv[32];
#pragma unroll
    for (int j = 0; j < 32; ++j)
      xv[j] = xb[(size_t)(c0 + j) * S_DIM + p];

    double acc[4] = {0.0, 0.0, 0.0, 0.0};
#pragma unroll
    for (int j = 0; j < 32; ++j) {
      const double xd = (double)xv[j];
      acc[0] += xd * (double)gate_w[0*256 + c0 + j];
      acc[1] += xd * (double)gate_w[1*256 + c0 + j];
      acc[2] += xd * (double)gate_w[2*256 + c0 + j];
      acc[3] += xd * (double)gate_w[3*256 + c0 + j];
    }

#pragma unroll
    for (int k = 0; k < 4; ++k) {
      bf16x8 blk = {bfq(xv[k*8+0]), bfq(xv[k*8+1]), bfq(xv[k*8+2]), bfq(xv[k*8+3]),
                    bfq(xv[k*8+4]), bfq(xv[k*8+5]), bfq(xv[k*8+6]), bfq(xv[k*8+7])};
      *(bf16x8*)(XsS + p*XST + c0 + k*8) = blk;
    }

    double* GateD = (double*)HsS;   // 64pos x 4e x 8grp fp64 = 16KB (alias)
#pragma unroll
    for (int e = 0; e < 4; ++e)
      GateD[(e*8 + wv)*64 + p] = acc[e];
  }
  __syncthreads();   // Xs staged AND gate partials written

  // ---- logits (fp64 reduce, fixed order) + top-2 + softmax, fused via shfl ----
  if (tid < 256) {
    const int p = tid >> 2;
    const int e = tid & 3;
    const double* GateD = (const double*)HsS;
    double s = (double)gate_b[e];
#pragma unroll
    for (int g2 = 0; g2 < 8; ++g2) s += GateD[(e*8 + g2)*64 + p];
    const float la = (float)s;              // l[e]
    const float lb = __shfl_xor(la, 1, 64); // l[e^1]
    const float lc = __shfl_xor(la, 2, 64); // l[e^2]
    const float ld = __shfl_xor(lb, 2, 64); // l[e^3]
    if (e == 0) {
      const float l0 = la, l1 = lb, l2 = lc, l3 = ld;
      int i1 = 0; float v1 = l0;
      if (l1 > v1) { v1 = l1; i1 = 1; }
      if (l2 > v1) { v1 = l2; i1 = 2; }
      if (l3 > v1) { v1 = l3; i1 = 3; }
      float v2 = -3.0e38f; int i2 = 0;
      if (i1 != 0 && l0 > v2) { v2 = l0; i2 = 0; }
      if (i1 != 1 && l1 > v2) { v2 = l1; i2 = 1; }
      if (i1 != 2 && l2 > v2) { v2 = l2; i2 = 2; }
      if (i1 != 3 && l3 > v2) { v2 = l3; i2 = 3; }
      const float wA = 1.0f / (1.0f + __expf(v2 - v1));
      const float wB = 1.0f - wA;
      Wgt[0][p] = (i1 == 0) ? wA : ((i2 == 0) ? wB : 0.0f);
      Wgt[1][p] = (i1 == 1) ? wA : ((i2 == 1) ? wB : 0.0f);
      Wgt[2][p] = (i1 == 2) ? wA : ((i2 == 2) ? wB : 0.0f);
      Wgt[3][p] = (i1 == 3) ? wA : ((i2 == 3) ? wB : 0.0f);
    }
  }
  __syncthreads();   // Wgt final (also: GateD fully consumed before H-scatter)

  f32x4 oacc[4][2];   // [Mt][t]: persistent out accumulator, K=1024 concat
#pragma unroll
  for (int i = 0; i < 4; ++i)
#pragma unroll
    for (int j = 0; j < 2; ++j) oacc[i][j] = (f32x4){0.f, 0.f, 0.f, 0.f};

  for (int e = 0; e < E_DIM; ++e) {
    const short* w1e = W1P + ((e*16 + wv*2)*8)*512 + lane*8;
    const bool dosync = (e > 0);   // wait for prev GEMM2's Hs readers

    gemm1_dense(XsS, HsS, w1e, b1 + e*256, &Wgt[e][0], wv, r, q, dosync);

    // GEMM2 prologue: first kc B-fragments, issued before the barrier
    const short* w2e = W2P + ((e*16 + wv*2)*8)*512 + lane*8;
    bf16x8 cw[2][2];
#pragma unroll
    for (int t = 0; t < 2; ++t) cw[0][t] = *(const bf16x8*)(w2e + (t*8 + 0)*512);

    __syncthreads();   // Hs complete (weighted scatter covers all 64 rows)

    // ---- GEMM2: oacc += H_e(64x256) @ W2_e^T slice, ring-2 prefetch ----
    {
      __builtin_amdgcn_s_setprio(1);
#pragma unroll
      for (int kc = 0; kc < 8; ++kc) {
        if (kc < 7) {
#pragma unroll
          for (int t = 0; t < 2; ++t)
            cw[(kc+1)&1][t] = *(const bf16x8*)(w2e + (t*8 + kc + 1)*512);
        }
        bf16x8 a[4];
#pragma unroll
        for (int Mt = 0; Mt < 4; ++Mt)
          a[Mt] = *(const bf16x8*)(HsS + (Mt*16 + r)*XST + kc*32 + q*8);
#pragma unroll
        for (int Mt = 0; Mt < 4; ++Mt)
#pragma unroll
          for (int t = 0; t < 2; ++t)
            oacc[Mt][t] = __builtin_amdgcn_mfma_f32_16x16x32_bf16(a[Mt], cw[kc&1][t], oacc[Mt][t], 0, 0, 0);
      }
      __builtin_amdgcn_s_setprio(0);
    }
    // no barrier here: next expert's GEMM1 compute doesn't touch Hs; the
    // barrier protecting Hs sits inside gemm1_dense, before its scatter.
  }

  // ---- O epilogue: direct stores. Lane holds 4 CONSECUTIVE positions per
  //      fragment (D row = q*4+reg): float4 res/store per (Mt,t). Reads Wgt
  //      (stable LDS, e-major -> f32x4 per expert) + regs: no barrier. ----
  {
    float b2v[2][4];   // [t][e] for c = wv*32 + t*16 + r
#pragma unroll
    for (int t = 0; t < 2; ++t) {
      const int c = wv*32 + t*16 + r;
#pragma unroll
      for (int e = 0; e < 4; ++e) b2v[t][e] = b2[e*256 + c];
    }
    float* ob = out + (size_t)b * C_DIM * S_DIM + s0;
#pragma unroll
    for (int Mt = 0; Mt < 4; ++Mt) {
      const int pb = Mt*16 + q*4;
      f32x4 wge[4];
#pragma unroll
      for (int e = 0; e < 4; ++e)
        wge[e] = *(const f32x4*)(&Wgt[e][pb]);
#pragma unroll
      for (int t = 0; t < 2; ++t) {
        const int c = wv*32 + t*16 + r;
        f32x4 v = oacc[Mt][t];
#pragma unroll
        for (int reg = 0; reg < 4; ++reg)
          v[reg] += wge[0][reg]*b2v[t][0] + wge[1][reg]*b2v[t][1]
                  + wge[2][reg]*b2v[t][2] + wge[3][reg]*b2v[t][3];
        const float4 xr = *(const float4*)(xb + (size_t)c*S_DIM + pb);
        float4 res;
        res.x = v[0] + xr.x; res.y = v[1] + xr.y;
        res.z = v[2] + xr.z; res.w = v[3] + xr.w;
        *(float4*)(ob + (size_t)c*S_DIM + pb) = res;
      }
    }
  }
}

extern "C" void kernel_launch(void* const* d_in, const int* in_sizes, int n_in,
                              void* d_out, int out_size, void* d_ws, size_t ws_size,
                              hipStream_t stream)
{
  (void)in_sizes; (void)n_in; (void)out_size; (void)ws_size;
  const float* x      = (const float*)d_in[0];
  const float* gate_w = (const float*)d_in[1];
  const float* gate_b = (const float*)d_in[2];
  const float* w1     = (const float*)d_in[3];
  const float* b1     = (const float*)d_in[4];
  const float* w2     = (const float*)d_in[5];
  const float* b2     = (const float*)d_in[6];
  float* out = (float*)d_out;
  __hip_bfloat16* wpack = (__hip_bfloat16*)d_ws;   // needs 1 MiB of scratch

  prepack_kernel<<<256, 256, 0, stream>>>(w1, w2, wpack);
  moe_fused_kernel<<<512, 512, 0, stream>>>(x, gate_w, gate_b, b1, b2, wpack, out);
}